// Round 4
// baseline (392.229 us; speedup 1.0000x reference)
//
#include <hip/hip_runtime.h>
#include <math.h>

// Problem constants
#define BB 32
#define TT 1024
#define DD 256
#define NBLK 1024
#define CHB 32            // chunk-blocks per batch (1024/32)

// Flag tags — must differ from 0xAAAAAAAA poison (documented) and from each other.
#define TAGP 0x13570000u
#define TAGW 0x24680000u
#define TAGB 0x369C0000u

// Analytic collapse (verified R1):
//   out[b,t,d] = (t < len[b]) ? (1+W[b,d])*x[b,t,d] + (t==0 ? Bf[b,d] : 0) : 0
// with c = (sum_t x)/len, W = MLP_W(c), Bf = MLP_B(c), exact GELU.
//
// Single dispatch, 1024 blocks. All blocks co-resident (8 blk/CU capacity vs
// 4 needed), so intra-kernel acquire/release flag waits are deadlock-free.
// R2 showed runtime grid.sync() ~100us/barrier; hand-rolled flags avoid it.

__global__ __launch_bounds__(256, 4)
void fused(const float* __restrict__ x, const int* __restrict__ len,
           const float* __restrict__ Ww1_w, const float* __restrict__ Ww1_b,
           const float* __restrict__ Ww2_w, const float* __restrict__ Ww2_b,
           const float* __restrict__ Wb1_w, const float* __restrict__ Wb1_b,
           const float* __restrict__ Wb2_w, const float* __restrict__ Wb2_b,
           float* __restrict__ out,
           float* __restrict__ partial,      // ws [1024][256]
           float* __restrict__ Wout,         // ws [32][256]
           float* __restrict__ Bout,         // ws [32][256]
           unsigned* __restrict__ pflag,     // ws [1024]
           unsigned* __restrict__ wdone,     // ws [32]
           unsigned* __restrict__ bdone)     // ws [32]
{
    __shared__ float4 red[4][64];   // 4 KB
    __shared__ float  csh[DD];      // 1 KB
    __shared__ float  hsh[DD];      // 1 KB

    const int g    = blockIdx.x;          // 0..1023
    const int tid  = threadIdx.x;
    const int wave = tid >> 6;
    const int lane = tid & 63;
    const int b    = g >> 5;              // batch of this block's rows
    const int row0 = g * 32;

    // ---------------- Phase 1: partial sum of this block's 32 rows ----------
    {
        const float4* xr = (const float4*)(x + (size_t)(row0 + wave * 8) * DD);
        float4 s; s.x = 0.f; s.y = 0.f; s.z = 0.f; s.w = 0.f;
#pragma unroll
        for (int r = 0; r < 8; ++r) {
            float4 v = xr[(size_t)r * 64 + lane];
            s.x += v.x; s.y += v.y; s.z += v.z; s.w += v.w;
        }
        red[wave][lane] = s;
    }
    __syncthreads();
    if (tid < 64) {
        float4 a = red[0][tid], c2 = red[1][tid], c3 = red[2][tid], c4 = red[3][tid];
        float4 o;
        o.x = (a.x + c2.x) + (c3.x + c4.x);
        o.y = (a.y + c2.y) + (c3.y + c4.y);
        o.z = (a.z + c2.z) + (c3.z + c4.z);
        o.w = (a.w + c2.w) + (c3.w + c4.w);
        ((float4*)(partial + (size_t)g * DD))[tid] = o;
    }
    __syncthreads();
    if (tid == 0)
        __hip_atomic_store(&pflag[g], TAGP | (unsigned)g,
                           __ATOMIC_RELEASE, __HIP_MEMORY_SCOPE_AGENT);

    // ---------------- Phase 2: 64 finisher blocks (g%16==0) run the MLPs ----
    if ((g & 15) == 0) {
        const int k   = g >> 4;        // 0..63
        const int fb  = k >> 1;        // == g/32 == this block's own batch
        const int mlp = k & 1;
        if (tid < CHB) {
            const int src = fb * CHB + tid;
            const unsigned want = TAGP | (unsigned)src;
            while (__hip_atomic_load(&pflag[src], __ATOMIC_ACQUIRE,
                                     __HIP_MEMORY_SCOPE_AGENT) != want)
                __builtin_amdgcn_s_sleep(2);
        }
        __syncthreads();
        {   // c[fb][tid] = (sum of 32 chunk partials) / len[fb]
            float s = 0.f;
            const float* pp = partial + (size_t)(fb * CHB) * DD + tid;
#pragma unroll
            for (int ch = 0; ch < CHB; ++ch) s += pp[(size_t)ch * DD];
            csh[tid] = s / (float)len[fb];
        }
        __syncthreads();
        const float* w1 = mlp ? Wb1_w : Ww1_w;
        const float* b1 = mlp ? Wb1_b : Ww1_b;
        const float* w2 = mlp ? Wb2_w : Ww2_w;
        const float* b2 = mlp ? Wb2_b : Ww2_b;
        float* op       = mlp ? Bout  : Wout;
        {   // layer 1: h[j] = gelu_exact(c . w1[j] + b1[j])
            const float4* wr = (const float4*)(w1 + (size_t)tid * DD);
            const float4* cc = (const float4*)csh;
            float s = 0.f;
#pragma unroll 8
            for (int kk = 0; kk < 64; ++kk) {
                float4 w = wr[kk];
                float4 c4 = cc[kk];
                s += w.x * c4.x + w.y * c4.y + w.z * c4.z + w.w * c4.w;
            }
            float v = s + b1[tid];
            hsh[tid] = 0.5f * v * (1.0f + erff(v * 0.70710678118654752440f));
        }
        __syncthreads();
        {   // layer 2: op[fb][d] = h . w2[d] + b2[d]
            const float4* wr = (const float4*)(w2 + (size_t)tid * DD);
            const float4* hh = (const float4*)hsh;
            float s = 0.f;
#pragma unroll 8
            for (int kk = 0; kk < 64; ++kk) {
                float4 w = wr[kk];
                float4 h4 = hh[kk];
                s += w.x * h4.x + w.y * h4.y + w.z * h4.z + w.w * h4.w;
            }
            op[fb * DD + tid] = s + b2[tid];
        }
        __syncthreads();
        if (tid == 0) {
            if (mlp)
                __hip_atomic_store(&bdone[fb], TAGB | (unsigned)fb,
                                   __ATOMIC_RELEASE, __HIP_MEMORY_SCOPE_AGENT);
            else
                __hip_atomic_store(&wdone[fb], TAGW | (unsigned)fb,
                                   __ATOMIC_RELEASE, __HIP_MEMORY_SCOPE_AGENT);
        }
    }

    // ---------------- Phase 3: wait for own batch's W,B then apply ----------
    if (tid == 0) {
        const unsigned want = TAGW | (unsigned)b;
        while (__hip_atomic_load(&wdone[b], __ATOMIC_ACQUIRE,
                                 __HIP_MEMORY_SCOPE_AGENT) != want)
            __builtin_amdgcn_s_sleep(2);
    }
    if (tid == 1) {
        const unsigned want = TAGB | (unsigned)b;
        while (__hip_atomic_load(&bdone[b], __ATOMIC_ACQUIRE,
                                 __HIP_MEMORY_SCOPE_AGENT) != want)
            __builtin_amdgcn_s_sleep(2);
    }
    __syncthreads();
    {
        const int L = len[b];
        const float4 w4 = ((const float4*)(Wout + b * DD))[lane];
        const float4 b4 = ((const float4*)(Bout + b * DD))[lane];
#pragma unroll
        for (int r = 0; r < 8; ++r) {
            const int row = row0 + wave * 8 + r;
            const int t   = row & (TT - 1);
            const size_t base = (size_t)row * DD;
            float4 res;
            if (t >= L) {
                res.x = 0.f; res.y = 0.f; res.z = 0.f; res.w = 0.f;
            } else {
                float4 x4 = ((const float4*)(x + base))[lane];
                res.x = x4.x + w4.x * x4.x;
                res.y = x4.y + w4.y * x4.y;
                res.z = x4.z + w4.z * x4.z;
                res.w = x4.w + w4.w * x4.w;
                if (t == 0) { res.x += b4.x; res.y += b4.y; res.z += b4.z; res.w += b4.w; }
            }
            ((float4*)(out + base))[lane] = res;
        }
    }
}

// Workspace layout (32-bit words):
//   partial : 262144 @ 0
//   Wout    :   8192 @ 262144
//   Bout    :   8192 @ 270336
//   pflag   :   1024 @ 278528
//   wdone   :     32 @ 279552
//   bdone   :     32 @ 279584
// total 279616 words ~= 1.07 MiB
extern "C" void kernel_launch(void* const* d_in, const int* in_sizes, int n_in,
                              void* d_out, int out_size, void* d_ws, size_t ws_size,
                              hipStream_t stream) {
    const float* x     = (const float*)d_in[0];
    const int*   len   = (const int*)d_in[1];
    const float* Ww1_w = (const float*)d_in[2];
    const float* Ww1_b = (const float*)d_in[3];
    const float* Ww2_w = (const float*)d_in[4];
    const float* Ww2_b = (const float*)d_in[5];
    const float* Wb1_w = (const float*)d_in[6];
    const float* Wb1_b = (const float*)d_in[7];
    const float* Wb2_w = (const float*)d_in[8];
    const float* Wb2_b = (const float*)d_in[9];
    float* out = (float*)d_out;

    float*    ws      = (float*)d_ws;
    float*    partial = ws;
    float*    Wout    = ws + 262144;
    float*    Bout    = ws + 270336;
    unsigned* pflag   = (unsigned*)(ws + 278528);
    unsigned* wdone   = (unsigned*)(ws + 279552);
    unsigned* bdone   = (unsigned*)(ws + 279584);

    fused<<<NBLK, 256, 0, stream>>>(x, len,
                                    Ww1_w, Ww1_b, Ww2_w, Ww2_b,
                                    Wb1_w, Wb1_b, Wb2_w, Wb2_b,
                                    out, partial, Wout, Bout,
                                    pflag, wdone, bdone);
}

// Round 6
// 191.401 us; speedup vs baseline: 2.0492x; 2.0492x over previous
//
#include <hip/hip_runtime.h>
#include <math.h>

// Problem constants
#define BB 32
#define TT 1024
#define DD 256
#define NBLK1 1024
#define CHB 32            // chunk-blocks per batch (1024/32)

// Flag tag — differs from 0xAAAAAAAA ws-poison (validated in R4) for any g<1024.
#define TAGP 0x13570000u

// Analytic collapse (verified R1):
//   out[b,t,d] = (t < len[b]) ? (1+W[b,d])*x[b,t,d] + (t==0 ? Bf[b,d] : 0) : 0
// with c = (sum_t x)/len, W = MLP_W(c), Bf = MLP_B(c), exact GELU.
//
// Lessons: grid.sync() ~100us (R2). Acquire-loads in poll loops invalidate the
// XCD L2 every iteration -> 300us (R4). Here: relaxed polls + ONE acquire
// fence (__builtin_amdgcn_fence — __hip_atomic_fence doesn't exist, R5), only
// 64 polling blocks, and the apply pass is a separate dispatch so it needs no
// polling at all.

// ---------------------------------------------------------------------------
// K1: partial sums + (64 finisher blocks) c + both MLPs.
// ---------------------------------------------------------------------------
__global__ __launch_bounds__(256, 4)
void k_partial_mlp(const float* __restrict__ x, const int* __restrict__ len,
                   const float* __restrict__ Ww1_w, const float* __restrict__ Ww1_b,
                   const float* __restrict__ Ww2_w, const float* __restrict__ Ww2_b,
                   const float* __restrict__ Wb1_w, const float* __restrict__ Wb1_b,
                   const float* __restrict__ Wb2_w, const float* __restrict__ Wb2_b,
                   float* __restrict__ partial,   // ws [1024][256]
                   unsigned* __restrict__ pflag,  // ws [1024]
                   float* __restrict__ Wout,      // ws [32][256]
                   float* __restrict__ Bout)      // ws [32][256]
{
    __shared__ float4 red[4][64];
    __shared__ float  csh[DD];
    __shared__ float  hsh[DD];

    const int g    = blockIdx.x;          // 0..1023
    const int tid  = threadIdx.x;
    const int wave = tid >> 6;
    const int lane = tid & 63;
    const int row0 = g * 32;

    // Phase A: partial sum of this block's 32 rows (float4, coalesced).
    {
        const float4* xr = (const float4*)(x + (size_t)(row0 + wave * 8) * DD);
        float4 s; s.x = 0.f; s.y = 0.f; s.z = 0.f; s.w = 0.f;
#pragma unroll
        for (int r = 0; r < 8; ++r) {
            float4 v = xr[(size_t)r * 64 + lane];
            s.x += v.x; s.y += v.y; s.z += v.z; s.w += v.w;
        }
        red[wave][lane] = s;
    }
    __syncthreads();
    // Wave 0 (tid<64) owns ALL partial stores, so tid 0's release covers them
    // via its wave's vmcnt drain + L2 writeback.
    if (tid < 64) {
        float4 a = red[0][tid], c2 = red[1][tid], c3 = red[2][tid], c4 = red[3][tid];
        float4 o;
        o.x = (a.x + c2.x) + (c3.x + c4.x);
        o.y = (a.y + c2.y) + (c3.y + c4.y);
        o.z = (a.z + c2.z) + (c3.z + c4.z);
        o.w = (a.w + c2.w) + (c3.w + c4.w);
        ((float4*)(partial + (size_t)g * DD))[tid] = o;
        if (tid == 0)
            __hip_atomic_store(&pflag[g], TAGP | (unsigned)g,
                               __ATOMIC_RELEASE, __HIP_MEMORY_SCOPE_AGENT);
    }

    // Phase B: finisher blocks only — 2 per batch: g == fb*32 + {0,16}.
    if ((g & 15) != 0) return;
    const int fb  = g >> 5;            // this block's own batch
    const int mlp = (g >> 4) & 1;

    // Relaxed polling (no cache invalidates), one flag per thread.
    if (tid < CHB) {
        const int src = fb * CHB + tid;
        const unsigned want = TAGP | (unsigned)src;
        while (__hip_atomic_load(&pflag[src], __ATOMIC_RELAXED,
                                 __HIP_MEMORY_SCOPE_AGENT) != want)
            __builtin_amdgcn_s_sleep(4);
    }
    __syncthreads();
    // Single acquire fence to make the producers' partial stores visible.
    __builtin_amdgcn_fence(__ATOMIC_ACQUIRE, "agent");

    {   // c[fb][tid] = (sum of 32 chunk partials) / len[fb]
        float s = 0.f;
        const float* pp = partial + (size_t)(fb * CHB) * DD + tid;
#pragma unroll
        for (int ch = 0; ch < CHB; ++ch) s += pp[(size_t)ch * DD];
        csh[tid] = s / (float)len[fb];
    }
    __syncthreads();
    const float* w1 = mlp ? Wb1_w : Ww1_w;
    const float* b1 = mlp ? Wb1_b : Ww1_b;
    const float* w2 = mlp ? Wb2_w : Ww2_w;
    const float* b2 = mlp ? Wb2_b : Ww2_b;
    float* op       = mlp ? Bout  : Wout;
    {   // layer 1: h[j] = gelu_exact(c . w1[j] + b1[j])
        const float4* wr = (const float4*)(w1 + (size_t)tid * DD);
        const float4* cc = (const float4*)csh;
        float s = 0.f;
#pragma unroll 8
        for (int k = 0; k < 64; ++k) {
            float4 w = wr[k];
            float4 c4 = cc[k];
            s += w.x * c4.x + w.y * c4.y + w.z * c4.z + w.w * c4.w;
        }
        float v = s + b1[tid];
        hsh[tid] = 0.5f * v * (1.0f + erff(v * 0.70710678118654752440f));
    }
    __syncthreads();
    {   // layer 2: op[fb][d] = h . w2[d] + b2[d]
        const float4* wr = (const float4*)(w2 + (size_t)tid * DD);
        const float4* hh = (const float4*)hsh;
        float s = 0.f;
#pragma unroll 8
        for (int k = 0; k < 64; ++k) {
            float4 w = wr[k];
            float4 h4 = hh[k];
            s += w.x * h4.x + w.y * h4.y + w.z * h4.z + w.w * h4.w;
        }
        op[fb * DD + tid] = s + b2[tid];   // visible to K2 via dispatch boundary
    }
}

// ---------------------------------------------------------------------------
// K2: out[b,t,d] = (t<L) ? (1+W[b,d])*x + (t==0 ? B[b,d] : 0) : 0
// ---------------------------------------------------------------------------
__global__ __launch_bounds__(256)
void k_apply(const float* __restrict__ x, const int* __restrict__ len,
             const float* __restrict__ Wf, const float* __restrict__ Bf,
             float* __restrict__ out) {
    const int row  = blockIdx.x * 4 + (threadIdx.x >> 6);
    const int lane = threadIdx.x & 63;
    const int b = row >> 10;
    const int t = row & (TT - 1);
    const int L = len[b];
    const size_t base = (size_t)row * DD;
    float4* o4 = (float4*)(out + base);
    if (t >= L) {
        float4 z; z.x = 0.f; z.y = 0.f; z.z = 0.f; z.w = 0.f;
        o4[lane] = z;
        return;
    }
    float4 x4 = ((const float4*)(x + base))[lane];
    float4 w4 = ((const float4*)(Wf + b * DD))[lane];
    float4 r;
    r.x = x4.x + w4.x * x4.x;
    r.y = x4.y + w4.y * x4.y;
    r.z = x4.z + w4.z * x4.z;
    r.w = x4.w + w4.w * x4.w;
    if (t == 0) {
        float4 b4 = ((const float4*)(Bf + b * DD))[lane];
        r.x += b4.x; r.y += b4.y; r.z += b4.z; r.w += b4.w;
    }
    o4[lane] = r;
}

// Workspace (32-bit words): partial 262144 @ 0, Wout 8192 @ 262144,
// Bout 8192 @ 270336, pflag 1024 @ 278528.
extern "C" void kernel_launch(void* const* d_in, const int* in_sizes, int n_in,
                              void* d_out, int out_size, void* d_ws, size_t ws_size,
                              hipStream_t stream) {
    const float* x     = (const float*)d_in[0];
    const int*   len   = (const int*)d_in[1];
    const float* Ww1_w = (const float*)d_in[2];
    const float* Ww1_b = (const float*)d_in[3];
    const float* Ww2_w = (const float*)d_in[4];
    const float* Ww2_b = (const float*)d_in[5];
    const float* Wb1_w = (const float*)d_in[6];
    const float* Wb1_b = (const float*)d_in[7];
    const float* Wb2_w = (const float*)d_in[8];
    const float* Wb2_b = (const float*)d_in[9];
    float* out = (float*)d_out;

    float*    ws      = (float*)d_ws;
    float*    partial = ws;
    float*    Wout    = ws + 262144;
    float*    Bout    = ws + 270336;
    unsigned* pflag   = (unsigned*)(ws + 278528);

    k_partial_mlp<<<NBLK1, 256, 0, stream>>>(x, len,
                                             Ww1_w, Ww1_b, Ww2_w, Ww2_b,
                                             Wb1_w, Wb1_b, Wb2_w, Wb2_b,
                                             partial, pflag, Wout, Bout);
    k_apply<<<BB * TT / 4, 256, 0, stream>>>(x, len, Wout, Bout, out);
}

// Round 7
// 149.329 us; speedup vs baseline: 2.6266x; 1.2817x over previous
//
#include <hip/hip_runtime.h>
#include <math.h>

// Problem constants
#define BB 32
#define TT 1024
#define DD 256

// Analytic collapse (verified R1):
//   out[b,t,d] = (t < len[b]) ? (1+W[b,d])*x[b,t,d] + (t==0 ? Bf[b,d] : 0) : 0
// with c = (sum over FULL T of x)/len, W = MLP_W(c), Bf = MLP_B(c), exact GELU.
//
// Sync lessons (measured): grid.sync() ~100us (R2); acquire-poll ~100us (R4);
// relaxed-poll ~90us — stale L2 line until eviction (R6). => NO cross-block
// joins. This version: one dispatch, 64 blocks x 1024 threads, one block per
// (batch, half). Each block redundantly computes the full-batch mean + MLPs
// in-block (intra-block joins only), then applies its own 512 rows.

__global__ __launch_bounds__(1024, 1)
void k_all(const float* __restrict__ x, const int* __restrict__ len,
           const float* __restrict__ Ww1_w, const float* __restrict__ Ww1_b,
           const float* __restrict__ Ww2_w, const float* __restrict__ Ww2_b,
           const float* __restrict__ Wb1_w, const float* __restrict__ Wb1_b,
           const float* __restrict__ Wb2_w, const float* __restrict__ Wb2_b,
           float* __restrict__ out)
{
    __shared__ float4 red[16][64];   // 16 KB: per-wave phase-1 partials
    __shared__ float  csh[DD];       // c[b]
    __shared__ float  h0[DD];        // mlp0 hidden
    __shared__ float  h1[DD];        // mlp1 hidden
    __shared__ float  wsh[DD];       // W[b] (gain)
    __shared__ float  bsh[DD];       // Bf[b] (t==0 bias)

    const int g    = blockIdx.x;     // 0..63
    const int b    = g >> 1;
    const int half = g & 1;
    const int tid  = threadIdx.x;    // 0..1023
    const int wave = tid >> 6;       // 0..15
    const int lane = tid & 63;

    // ---- Phase 1: full-batch sum (redundant per half; twin read hits LLC) --
    {
        const float4* xr = (const float4*)(x + ((size_t)b * TT + (size_t)wave * 64) * DD);
        float4 s; s.x = 0.f; s.y = 0.f; s.z = 0.f; s.w = 0.f;
#pragma unroll 8
        for (int r = 0; r < 64; ++r) {
            float4 v = xr[(size_t)r * 64 + lane];
            s.x += v.x; s.y += v.y; s.z += v.z; s.w += v.w;
        }
        red[wave][lane] = s;
    }
    __syncthreads();
    if (tid < 64) {
        float4 s; s.x = 0.f; s.y = 0.f; s.z = 0.f; s.w = 0.f;
#pragma unroll
        for (int w = 0; w < 16; ++w) {
            float4 v = red[w][tid];
            s.x += v.x; s.y += v.y; s.z += v.z; s.w += v.w;
        }
        const float inv = 1.0f / (float)len[b];
        s.x *= inv; s.y *= inv; s.z *= inv; s.w *= inv;
        ((float4*)csh)[tid] = s;
    }
    __syncthreads();

    // ---- Phase 2: MLPs in-block. tid<256: mlp0 (W). tid 256..511 (half 0
    // only): mlp1 (Bf). Exact GELU. Barriers are executed by ALL threads.
    {   // layer 1
        if (tid < 256) {
            const float4* wr = (const float4*)(Ww1_w + (size_t)tid * DD);
            const float4* cc = (const float4*)csh;
            float s = 0.f;
#pragma unroll 8
            for (int k = 0; k < 64; ++k) {
                float4 w = wr[k]; float4 c4 = cc[k];
                s += w.x * c4.x + w.y * c4.y + w.z * c4.z + w.w * c4.w;
            }
            float v = s + Ww1_b[tid];
            h0[tid] = 0.5f * v * (1.0f + erff(v * 0.70710678118654752440f));
        } else if (tid < 512 && half == 0) {
            const int j = tid - 256;
            const float4* wr = (const float4*)(Wb1_w + (size_t)j * DD);
            const float4* cc = (const float4*)csh;
            float s = 0.f;
#pragma unroll 8
            for (int k = 0; k < 64; ++k) {
                float4 w = wr[k]; float4 c4 = cc[k];
                s += w.x * c4.x + w.y * c4.y + w.z * c4.z + w.w * c4.w;
            }
            float v = s + Wb1_b[j];
            h1[j] = 0.5f * v * (1.0f + erff(v * 0.70710678118654752440f));
        }
    }
    __syncthreads();
    {   // layer 2
        if (tid < 256) {
            const float4* wr = (const float4*)(Ww2_w + (size_t)tid * DD);
            const float4* hh = (const float4*)h0;
            float s = 0.f;
#pragma unroll 8
            for (int k = 0; k < 64; ++k) {
                float4 w = wr[k]; float4 h4 = hh[k];
                s += w.x * h4.x + w.y * h4.y + w.z * h4.z + w.w * h4.w;
            }
            wsh[tid] = s + Ww2_b[tid];
        } else if (tid < 512 && half == 0) {
            const int j = tid - 256;
            const float4* wr = (const float4*)(Wb2_w + (size_t)j * DD);
            const float4* hh = (const float4*)h1;
            float s = 0.f;
#pragma unroll 8
            for (int k = 0; k < 64; ++k) {
                float4 w = wr[k]; float4 h4 = hh[k];
                s += w.x * h4.x + w.y * h4.y + w.z * h4.z + w.w * h4.w;
            }
            bsh[j] = s + Wb2_b[j];
        }
    }
    __syncthreads();

    // ---- Phase 3: apply this block's 512 rows (t = half*512 + wave*32 + r) --
    {
        const int L = len[b];
        const float4 w4 = ((const float4*)wsh)[lane];
        float4 b4;
        if (half == 0) b4 = ((const float4*)bsh)[lane];
        else { b4.x = 0.f; b4.y = 0.f; b4.z = 0.f; b4.w = 0.f; }
#pragma unroll 4
        for (int r = 0; r < 32; ++r) {
            const int t = half * 512 + wave * 32 + r;
            const size_t base = ((size_t)b * TT + t) * DD;
            float4 res;
            if (t >= L) {
                res.x = 0.f; res.y = 0.f; res.z = 0.f; res.w = 0.f;
            } else {
                float4 x4 = ((const float4*)(x + base))[lane];
                res.x = x4.x + w4.x * x4.x;
                res.y = x4.y + w4.y * x4.y;
                res.z = x4.z + w4.z * x4.z;
                res.w = x4.w + w4.w * x4.w;
                if (t == 0) { res.x += b4.x; res.y += b4.y; res.z += b4.z; res.w += b4.w; }
            }
            ((float4*)(out + base))[lane] = res;
        }
    }
}

extern "C" void kernel_launch(void* const* d_in, const int* in_sizes, int n_in,
                              void* d_out, int out_size, void* d_ws, size_t ws_size,
                              hipStream_t stream) {
    const float* x     = (const float*)d_in[0];
    const int*   len   = (const int*)d_in[1];
    const float* Ww1_w = (const float*)d_in[2];
    const float* Ww1_b = (const float*)d_in[3];
    const float* Ww2_w = (const float*)d_in[4];
    const float* Ww2_b = (const float*)d_in[5];
    const float* Wb1_w = (const float*)d_in[6];
    const float* Wb1_b = (const float*)d_in[7];
    const float* Wb2_w = (const float*)d_in[8];
    const float* Wb2_b = (const float*)d_in[9];
    float* out = (float*)d_out;

    k_all<<<2 * BB, 1024, 0, stream>>>(x, len,
                                       Ww1_w, Ww1_b, Ww2_w, Ww2_b,
                                       Wb1_w, Wb1_b, Wb2_w, Wb2_b,
                                       out);
}